// Round 1
// baseline (891.004 us; speedup 1.0000x reference)
//
#include <hip/hip_runtime.h>
#include <cstdint>

constexpr int SEQ  = 2048;
constexpr int DIN  = 1024;
constexpr int DQK  = 128;
constexpr int NB   = 8;
constexpr int MTOT = NB * SEQ;   // 16384

struct GM { unsigned long long w[32]; };   // 2048-bit global-token mask

// ---------------------------------------------------------------------------
// Host-side reproduction of np.random.default_rng(0).choice(2048, 32, False).
// SeedSequence(0) -> PCG64(XSL-RR 128/64) -> Floyd's algorithm with Lemire
// 32-bit bounded draws (buffered next_uint32: low half first, high cached).
// The post-hoc shuffle only permutes order; the mask needs only the SET.
// ---------------------------------------------------------------------------
static void compute_gtok(unsigned long long bits[32]) {
  typedef unsigned __int128 u128;
  // --- SeedSequence(0): pool mixing ---
  uint32_t pool[4];
  uint32_t hc = 0x43b0d7e5u;               // INIT_A
  auto hashmix = [&hc](uint32_t v) -> uint32_t {
    v ^= hc; hc *= 0x931e8875u; v *= hc; v ^= v >> 16; return v;  // MULT_A
  };
  auto mixf = [](uint32_t x, uint32_t y) -> uint32_t {
    uint32_t r = x * 0xca01f9ddu - y * 0x4973f715u;  // MIX_MULT_L/R
    r ^= r >> 16; return r;
  };
  pool[0] = hashmix(0u);                    // entropy = [0]
  for (int i = 1; i < 4; ++i) pool[i] = hashmix(0u);
  for (int s = 0; s < 4; ++s)
    for (int d = 0; d < 4; ++d)
      if (s != d) pool[d] = mixf(pool[d], hashmix(pool[s]));
  // --- generate_state(4, uint64) ---
  uint32_t hb = 0x8b51f9ddu;               // INIT_B
  uint32_t st[8];
  for (int i = 0; i < 8; ++i) {
    uint32_t dv = pool[i & 3];
    dv ^= hb; hb *= 0x58f38dedu; dv *= hb; dv ^= dv >> 16;  // MULT_B
    st[i] = dv;
  }
  uint64_t sv[4];
  for (int i = 0; i < 4; ++i)
    sv[i] = (uint64_t)st[2 * i] | ((uint64_t)st[2 * i + 1] << 32);
  // --- PCG64 seeding ---
  const u128 MUL = ((u128)2549297995355413924ULL << 64) | (u128)4865540595714422341ULL;
  u128 initstate = ((u128)sv[0] << 64) | sv[1];
  u128 initseq   = ((u128)sv[2] << 64) | sv[3];
  u128 state = 0;
  u128 inc = (initseq << 1) | 1;
  state = state * MUL + inc;
  state += initstate;
  state = state * MUL + inc;
  bool has32 = false; uint32_t cache32 = 0;
  auto next64 = [&]() -> uint64_t {
    state = state * MUL + inc;
    uint64_t hi = (uint64_t)(state >> 64);
    uint64_t lo = (uint64_t)state;
    unsigned rot = (unsigned)(state >> 122);
    uint64_t x = hi ^ lo;
    return (x >> rot) | (x << ((64u - rot) & 63u));
  };
  auto next32 = [&]() -> uint32_t {
    if (has32) { has32 = false; return cache32; }
    uint64_t n = next64();
    has32 = true; cache32 = (uint32_t)(n >> 32);
    return (uint32_t)n;
  };
  // --- Floyd's algorithm: j = 2016..2047, val = Lemire32 bounded [0, j] ---
  bool in_set[SEQ];
  for (int i = 0; i < SEQ; ++i) in_set[i] = false;
  for (uint32_t j = 2016; j < 2048; ++j) {
    uint32_t rng_excl = j + 1;
    uint64_t m = (uint64_t)next32() * rng_excl;
    uint32_t leftover = (uint32_t)m;
    if (leftover < rng_excl) {
      uint32_t threshold = (0xFFFFFFFFu - j) % rng_excl;
      while (leftover < threshold) {
        m = (uint64_t)next32() * rng_excl;
        leftover = (uint32_t)m;
      }
    }
    uint32_t val = (uint32_t)(m >> 32);
    if (in_set[val]) in_set[j] = true;
    else in_set[val] = true;
  }
  for (int i = 0; i < 32; ++i) bits[i] = 0ULL;
  for (int t = 0; t < SEQ; ++t)
    if (in_set[t]) bits[t >> 6] |= (1ULL << (t & 63));
}

__device__ __forceinline__ bool gbit(const GM& g, int j) {
  return (g.w[j >> 6] >> (j & 63)) & 1ULL;
}

// ---------------------------------------------------------------------------
// Projection: OUT[m][n] = sum_k X[m][k] * W[n][k] + b[n]
// grid.x = M/64, grid.y = 3 (q/k/v). 64x128 tile, K-chunk 32, fp32.
// ---------------------------------------------------------------------------
__global__ __launch_bounds__(256) void proj_kernel(
    const float* __restrict__ xq, const float* __restrict__ xk, const float* __restrict__ xv,
    const float* __restrict__ Wq, const float* __restrict__ bq,
    const float* __restrict__ Wk, const float* __restrict__ bk,
    const float* __restrict__ Wv, const float* __restrict__ bv,
    float* __restrict__ Qo, float* __restrict__ Ko, float* __restrict__ Vo)
{
  const int which = blockIdx.y;
  const float* X    = (which == 0) ? xq : (which == 1) ? xk : xv;
  const float* W    = (which == 0) ? Wq : (which == 1) ? Wk : Wv;
  const float* bias = (which == 0) ? bq : (which == 1) ? bk : bv;
  float* OUT        = (which == 0) ? Qo : (which == 1) ? Ko : Vo;

  __shared__ float Xs[64][36];    // +4 pad: bank-safe, keeps 16B alignment
  __shared__ float Ws[128][36];

  const int tid = threadIdx.x;
  const int ty = tid >> 4, tx = tid & 15;
  const int m0 = blockIdx.x * 64;

  float acc[4][8];
#pragma unroll
  for (int i = 0; i < 4; ++i)
#pragma unroll
    for (int j = 0; j < 8; ++j) acc[i][j] = 0.0f;

  for (int kb = 0; kb < DIN; kb += 32) {
#pragma unroll
    for (int i = 0; i < 2; ++i) {          // X tile 64x32 = 512 float4
      int f = tid + i * 256;
      int r = f >> 3, c4 = f & 7;
      *(float4*)&Xs[r][c4 * 4] =
          *(const float4*)&X[(size_t)(m0 + r) * DIN + kb + c4 * 4];
    }
#pragma unroll
    for (int i = 0; i < 4; ++i) {          // W tile 128x32 = 1024 float4
      int f = tid + i * 256;
      int r = f >> 3, c4 = f & 7;
      *(float4*)&Ws[r][c4 * 4] =
          *(const float4*)&W[(size_t)r * DIN + kb + c4 * 4];
    }
    __syncthreads();
#pragma unroll
    for (int kk = 0; kk < 32; kk += 4) {
      float4 a4[4], b4[8];
#pragma unroll
      for (int i = 0; i < 4; ++i) a4[i] = *(float4*)&Xs[ty * 4 + i][kk];
#pragma unroll
      for (int j = 0; j < 8; ++j) b4[j] = *(float4*)&Ws[tx + j * 16][kk];
#pragma unroll
      for (int i = 0; i < 4; ++i)
#pragma unroll
        for (int j = 0; j < 8; ++j)
          acc[i][j] += a4[i].x * b4[j].x + a4[i].y * b4[j].y +
                       a4[i].z * b4[j].z + a4[i].w * b4[j].w;
    }
    __syncthreads();
  }
#pragma unroll
  for (int i = 0; i < 4; ++i) {
    const int m = m0 + ty * 4 + i;
#pragma unroll
    for (int j = 0; j < 8; ++j) {
      const int n = tx + j * 16;
      OUT[(size_t)m * DQK + n] = acc[i][j] + bias[n];
    }
  }
}

// ---------------------------------------------------------------------------
// Flash-style attention with causal + global-token mask.
// grid.x = SEQ/32 q-tiles, grid.y = batch. 256 threads.
// Online softmax with finite sentinel (-1e30): every row sees its diagonal
// in k-tile 0, so m stays finite after the first tile -> no NaN paths.
// ---------------------------------------------------------------------------
__global__ __launch_bounds__(256) void attn_kernel(
    const float* __restrict__ Q, const float* __restrict__ K,
    const float* __restrict__ V, float* __restrict__ Out, GM g)
{
  __shared__ float Qs[32][132];
  __shared__ float Ks[32][132];
  __shared__ float Vs[32][132];
  __shared__ float Ps[32][33];
  __shared__ float mrow[32], lrow[32], arow[32];

  const int tid = threadIdx.x;
  const int b   = blockIdx.y;
  const int qt  = blockIdx.x;
  const int qs  = qt * 32;
  const int qend = qs + 31;
  const float inv_scale = 0.08838834764831845f;  // 1/sqrt(128)
  const float NEG = -1e30f;

  const float* Qb = Q + (size_t)b * SEQ * DQK;
  const float* Kb = K + (size_t)b * SEQ * DQK;
  const float* Vb = V + (size_t)b * SEQ * DQK;

#pragma unroll
  for (int i = 0; i < 4; ++i) {            // Q tile 32x128
    int f = tid + i * 256;
    int r = f >> 5, c4 = f & 31;
    *(float4*)&Qs[r][c4 * 4] =
        *(const float4*)&Qb[(size_t)(qs + r) * DQK + c4 * 4];
  }
  if (tid < 32) { mrow[tid] = NEG; lrow[tid] = 0.0f; }

  const int orow = tid >> 3;               // output row owned by this thread
  const int dby  = (tid & 7) * 4;          // interleaved float4 chunks
  float O[16];
#pragma unroll
  for (int j = 0; j < 16; ++j) O[j] = 0.0f;

  const bool grow = ((g.w[qt >> 1] >> ((qt & 1) * 32)) & 0xFFFFFFFFULL) != 0ULL;
  const int sr = tid >> 4, sc = tid & 15;

  for (int kt = 0; kt < 64; ++kt) {
    const int ks0 = kt * 32;
    const bool gcol = ((g.w[kt >> 1] >> ((kt & 1) * 32)) & 0xFFFFFFFFULL) != 0ULL;
    if (!((ks0 <= qend) || gcol || grow)) continue;

    __syncthreads();                       // protect Ks/Vs/Ps reuse
#pragma unroll
    for (int i = 0; i < 4; ++i) {          // K,V tiles 32x128 each
      int f = tid + i * 256;
      int r = f >> 5, c4 = f & 31;
      *(float4*)&Ks[r][c4 * 4] =
          *(const float4*)&Kb[(size_t)(ks0 + r) * DQK + c4 * 4];
      *(float4*)&Vs[r][c4 * 4] =
          *(const float4*)&Vb[(size_t)(ks0 + r) * DQK + c4 * 4];
    }
    __syncthreads();

    // ---- scores: each thread computes 2x2 of the 32x32 S-tile ----
    float d00 = 0.f, d01 = 0.f, d10 = 0.f, d11 = 0.f;
#pragma unroll 4
    for (int c = 0; c < DQK; c += 4) {
      float4 qa  = *(float4*)&Qs[sr][c];
      float4 qb2 = *(float4*)&Qs[sr + 16][c];
      float4 ka  = *(float4*)&Ks[sc][c];
      float4 kb2 = *(float4*)&Ks[sc + 16][c];
      d00 += qa.x * ka.x  + qa.y * ka.y  + qa.z * ka.z  + qa.w * ka.w;
      d01 += qa.x * kb2.x + qa.y * kb2.y + qa.z * kb2.z + qa.w * kb2.w;
      d10 += qb2.x * ka.x  + qb2.y * ka.y  + qb2.z * ka.z  + qb2.w * ka.w;
      d11 += qb2.x * kb2.x + qb2.y * kb2.y + qb2.z * kb2.z + qb2.w * kb2.w;
    }
    {
      const int i0 = qs + sr, i1 = qs + sr + 16;
      const int j0 = ks0 + sc, j1 = ks0 + sc + 16;
      const bool gi0 = gbit(g, i0), gi1 = gbit(g, i1);
      const bool gj0 = gbit(g, j0), gj1 = gbit(g, j1);
      Ps[sr][sc]           = ((j0 <= i0) || gj0 || gi0) ? d00 * inv_scale : NEG;
      Ps[sr][sc + 16]      = ((j1 <= i0) || gj1 || gi0) ? d01 * inv_scale : NEG;
      Ps[sr + 16][sc]      = ((j0 <= i1) || gj0 || gi1) ? d10 * inv_scale : NEG;
      Ps[sr + 16][sc + 16] = ((j1 <= i1) || gj1 || gi1) ? d11 * inv_scale : NEG;
    }
    __syncthreads();

    // ---- online softmax: per-row max / rescale factor ----
    if (tid < 32) {
      float mx = NEG;
#pragma unroll
      for (int c2 = 0; c2 < 32; ++c2) mx = fmaxf(mx, Ps[tid][c2]);
      const float mold = mrow[tid];
      const float mnew = fmaxf(mold, mx);
      mrow[tid] = mnew;
      arow[tid] = __expf(mold - mnew);     // 0 on first tile, else <=1
    }
    __syncthreads();
    {
      const float m0r = mrow[sr], m1r = mrow[sr + 16];
      Ps[sr][sc]           = __expf(Ps[sr][sc]           - m0r);
      Ps[sr][sc + 16]      = __expf(Ps[sr][sc + 16]      - m0r);
      Ps[sr + 16][sc]      = __expf(Ps[sr + 16][sc]      - m1r);
      Ps[sr + 16][sc + 16] = __expf(Ps[sr + 16][sc + 16] - m1r);
    }
    __syncthreads();
    if (tid < 32) {
      float s = 0.0f;
#pragma unroll
      for (int c2 = 0; c2 < 32; ++c2) s += Ps[tid][c2];
      lrow[tid] = lrow[tid] * arow[tid] + s;
    }

    // ---- O update: O = alpha*O + P @ V-tile ----
    const float al = arow[orow];
#pragma unroll
    for (int j = 0; j < 16; ++j) O[j] *= al;
    for (int kk = 0; kk < 32; ++kk) {
      const float p = Ps[orow][kk];
#pragma unroll
      for (int t = 0; t < 4; ++t) {
        const float4 vv = *(float4*)&Vs[kk][dby + t * 32];
        O[t * 4 + 0] += p * vv.x;
        O[t * 4 + 1] += p * vv.y;
        O[t * 4 + 2] += p * vv.z;
        O[t * 4 + 3] += p * vv.w;
      }
    }
  }
  __syncthreads();
  const float invl = 1.0f / lrow[orow];
  float* outp = Out + ((size_t)b * SEQ + qs + orow) * DQK;
#pragma unroll
  for (int t = 0; t < 4; ++t) {
    float4 o4 = make_float4(O[t * 4 + 0] * invl, O[t * 4 + 1] * invl,
                            O[t * 4 + 2] * invl, O[t * 4 + 3] * invl);
    *(float4*)&outp[dby + t * 32] = o4;
  }
}

// ---------------------------------------------------------------------------
extern "C" void kernel_launch(void* const* d_in, const int* in_sizes, int n_in,
                              void* d_out, int out_size, void* d_ws, size_t ws_size,
                              hipStream_t stream) {
  const float* q  = (const float*)d_in[0];
  const float* k  = (const float*)d_in[1];
  const float* v  = (const float*)d_in[2];
  const float* Wq = (const float*)d_in[3];
  const float* bq = (const float*)d_in[4];
  const float* Wk = (const float*)d_in[5];
  const float* bk = (const float*)d_in[6];
  const float* Wv = (const float*)d_in[7];
  const float* bv = (const float*)d_in[8];
  float* out = (float*)d_out;

  float* Qo = (float*)d_ws;                      // 3 x 16384 x 128 fp32 = 24 MB
  float* Ko = Qo + (size_t)MTOT * DQK;
  float* Vo = Ko + (size_t)MTOT * DQK;

  GM g;
  compute_gtok(g.w);                             // deterministic, host CPU only

  dim3 pgrid(MTOT / 64, 3);
  hipLaunchKernelGGL(proj_kernel, pgrid, dim3(256), 0, stream,
                     q, k, v, Wq, bq, Wk, bk, Wv, bv, Qo, Ko, Vo);

  dim3 agrid(SEQ / 32, NB);
  hipLaunchKernelGGL(attn_kernel, agrid, dim3(256), 0, stream,
                     Qo, Ko, Vo, out, g);
}

// Round 2
// 323.362 us; speedup vs baseline: 2.7554x; 2.7554x over previous
//
#include <hip/hip_runtime.h>
#include <cstdint>

constexpr int SEQ  = 2048;
constexpr int DIN  = 1024;
constexpr int DQK  = 128;
constexpr int NB   = 8;
constexpr int MTOT = NB * SEQ;   // 16384
constexpr float INV_SCALE = 0.08838834764831845f;  // 1/sqrt(128)

typedef __attribute__((ext_vector_type(8))) short  short8;
typedef __attribute__((ext_vector_type(4))) float  floatx4;
typedef __attribute__((ext_vector_type(4))) int    intx4;

struct GM { unsigned long long w[32]; };   // 2048-bit global-token mask

// ---------------------------------------------------------------------------
// Host-side reproduction of np.random.default_rng(0).choice(2048, 32, False).
// (verified correct in Round 1: absmax 9.8e-4)
// ---------------------------------------------------------------------------
static void compute_gtok(unsigned long long bits[32]) {
  typedef unsigned __int128 u128;
  uint32_t pool[4];
  uint32_t hc = 0x43b0d7e5u;
  auto hashmix = [&hc](uint32_t v) -> uint32_t {
    v ^= hc; hc *= 0x931e8875u; v *= hc; v ^= v >> 16; return v;
  };
  auto mixf = [](uint32_t x, uint32_t y) -> uint32_t {
    uint32_t r = x * 0xca01f9ddu - y * 0x4973f715u;
    r ^= r >> 16; return r;
  };
  pool[0] = hashmix(0u);
  for (int i = 1; i < 4; ++i) pool[i] = hashmix(0u);
  for (int s = 0; s < 4; ++s)
    for (int d = 0; d < 4; ++d)
      if (s != d) pool[d] = mixf(pool[d], hashmix(pool[s]));
  uint32_t hb = 0x8b51f9ddu;
  uint32_t st[8];
  for (int i = 0; i < 8; ++i) {
    uint32_t dv = pool[i & 3];
    dv ^= hb; hb *= 0x58f38dedu; dv *= hb; dv ^= dv >> 16;
    st[i] = dv;
  }
  uint64_t sv[4];
  for (int i = 0; i < 4; ++i)
    sv[i] = (uint64_t)st[2 * i] | ((uint64_t)st[2 * i + 1] << 32);
  const u128 MUL = ((u128)2549297995355413924ULL << 64) | (u128)4865540595714422341ULL;
  u128 initstate = ((u128)sv[0] << 64) | sv[1];
  u128 initseq   = ((u128)sv[2] << 64) | sv[3];
  u128 state = 0;
  u128 inc = (initseq << 1) | 1;
  state = state * MUL + inc;
  state += initstate;
  state = state * MUL + inc;
  bool has32 = false; uint32_t cache32 = 0;
  auto next64 = [&]() -> uint64_t {
    state = state * MUL + inc;
    uint64_t hi = (uint64_t)(state >> 64);
    uint64_t lo = (uint64_t)state;
    unsigned rot = (unsigned)(state >> 122);
    uint64_t x = hi ^ lo;
    return (x >> rot) | (x << ((64u - rot) & 63u));
  };
  auto next32 = [&]() -> uint32_t {
    if (has32) { has32 = false; return cache32; }
    uint64_t n = next64();
    has32 = true; cache32 = (uint32_t)(n >> 32);
    return (uint32_t)n;
  };
  bool in_set[SEQ];
  for (int i = 0; i < SEQ; ++i) in_set[i] = false;
  for (uint32_t j = 2016; j < 2048; ++j) {
    uint32_t rng_excl = j + 1;
    uint64_t m = (uint64_t)next32() * rng_excl;
    uint32_t leftover = (uint32_t)m;
    if (leftover < rng_excl) {
      uint32_t threshold = (0xFFFFFFFFu - j) % rng_excl;
      while (leftover < threshold) {
        m = (uint64_t)next32() * rng_excl;
        leftover = (uint32_t)m;
      }
    }
    uint32_t val = (uint32_t)(m >> 32);
    if (in_set[val]) in_set[j] = true;
    else in_set[val] = true;
  }
  for (int i = 0; i < 32; ++i) bits[i] = 0ULL;
  for (int t = 0; t < SEQ; ++t)
    if (in_set[t]) bits[t >> 6] |= (1ULL << (t & 63));
}

// ---------------------------------------------------------------------------
// helpers
// ---------------------------------------------------------------------------
__device__ __forceinline__ unsigned short bfr(float x) {   // fp32 -> bf16 RNE
  unsigned u = __float_as_uint(x);
  return (unsigned short)((u + 0x7FFFu + ((u >> 16) & 1u)) >> 16);
}
__device__ __forceinline__ float bf2f(unsigned short h) {
  return __uint_as_float(((unsigned)h) << 16);
}
__device__ __forceinline__ void ldsld16(const void* g, void* l) {
  __builtin_amdgcn_global_load_lds(
      (const __attribute__((address_space(1))) unsigned int*)g,
      (__attribute__((address_space(3))) unsigned int*)l, 16, 0, 0);
}
__device__ __forceinline__ bool gbit(const GM& g, int j) {
  return (g.w[j >> 6] >> (j & 63)) & 1ULL;
}
__device__ __forceinline__ unsigned long long pk4(const unsigned short h[4]) {
  return (unsigned long long)h[0] | ((unsigned long long)h[1] << 16) |
         ((unsigned long long)h[2] << 32) | ((unsigned long long)h[3] << 48);
}

// ---------------------------------------------------------------------------
// Kernel 0: convert W (3 x [128][1024] fp32) to hi/lo bf16 planes (flat).
// ---------------------------------------------------------------------------
__global__ __launch_bounds__(256) void wconv_kernel(
    const float* __restrict__ Wq, const float* __restrict__ Wk, const float* __restrict__ Wv,
    unsigned short* __restrict__ Whi, unsigned short* __restrict__ Wlo) {
  const float* W = blockIdx.y == 0 ? Wq : blockIdx.y == 1 ? Wk : Wv;
  size_t base = (size_t)blockIdx.y * DQK * DIN;
  int e = (blockIdx.x * 256 + threadIdx.x) * 4;
  float4 x = *(const float4*)&W[e];
  float xs[4] = {x.x, x.y, x.z, x.w};
  unsigned short h[4], l[4];
#pragma unroll
  for (int i = 0; i < 4; ++i) { h[i] = bfr(xs[i]); l[i] = bfr(xs[i] - bf2f(h[i])); }
  *(unsigned long long*)&Whi[base + e] = pk4(h);
  *(unsigned long long*)&Wlo[base + e] = pk4(l);
}

// ---------------------------------------------------------------------------
// Kernel 1: projections via bf16 MFMA with hi/lo split (fp32-accurate).
// OUT[m][n] = sum_k X[m][k]*W[n][k] + b[n].
// 128x128 block tile, 4 waves of 64x64 (4x4 of 16x16x32), K-chunk 64.
// which 0/1 -> Q/K bf16 [s][d]; which 2 -> Vt hi/lo bf16 [b][d][s].
// LDS XOR-swizzled (group g stored at g^(row&7)) for bank-balanced b128 reads.
// ---------------------------------------------------------------------------
__global__ __launch_bounds__(256, 2) void proj_kernel(
    const float* __restrict__ xq, const float* __restrict__ xk, const float* __restrict__ xv,
    const unsigned short* __restrict__ Whi, const unsigned short* __restrict__ Wlo,
    const float* __restrict__ bq, const float* __restrict__ bk, const float* __restrict__ bv,
    unsigned short* __restrict__ Qb, unsigned short* __restrict__ Kb,
    unsigned short* __restrict__ Vth, unsigned short* __restrict__ Vtl) {
  const int which = blockIdx.y;
  const float* X    = which == 0 ? xq : which == 1 ? xk : xv;
  const float* bias = which == 0 ? bq : which == 1 ? bk : bv;
  const int m0 = blockIdx.x * 128;

  __shared__ unsigned short sm[4][8192];  // Xhi, Xlo, Whi, Wlo tiles [128][64]

  const int tid = threadIdx.x;
  const int w = tid >> 6, lane = tid & 63, l15 = lane & 15, quad = lane >> 4;
  const int mh = (w >> 1) * 64, nh = (w & 1) * 64;

  floatx4 acc[4][4] = {};
  float biasv[4];
#pragma unroll
  for (int j = 0; j < 4; ++j) biasv[j] = bias[nh + j * 16 + l15];

  const unsigned short* WhiP = Whi + (size_t)which * DQK * DIN;
  const unsigned short* WloP = Wlo + (size_t)which * DQK * DIN;

  for (int kb = 0; kb < DIN; kb += 64) {
    __syncthreads();
    // --- stage X: fp32 -> hi/lo bf16 planes, swizzled ---
#pragma unroll
    for (int i = 0; i < 8; ++i) {
      int f = tid + i * 256;
      int r = f >> 4, c4 = f & 15;
      float4 x = *(const float4*)&X[(size_t)(m0 + r) * DIN + kb + c4 * 4];
      float xs[4] = {x.x, x.y, x.z, x.w};
      unsigned short hh[4], ll[4];
#pragma unroll
      for (int t = 0; t < 4; ++t) { hh[t] = bfr(xs[t]); ll[t] = bfr(xs[t] - bf2f(hh[t])); }
      int off = r * 64 + (((c4 >> 1) ^ (r & 7)) * 8) + (c4 & 1) * 4;
      *(unsigned long long*)&sm[0][off] = pk4(hh);
      *(unsigned long long*)&sm[1][off] = pk4(ll);
    }
    // --- stage W hi/lo planes via global_load_lds (gather applies swizzle) ---
#pragma unroll
    for (int i = 0; i < 8; ++i) {
      int c = w * 8 + i;                 // 0..31: plane = c>>4, chunk cc = c&15
      int plane = c >> 4, cc = c & 15;
      int F = cc * 1024 + lane * 16;     // byte in 16KB plane tile
      int n = F >> 7, gs = (F >> 4) & 7, gl = gs ^ (n & 7);
      const unsigned short* gp = (plane ? WloP : WhiP) + (size_t)n * DIN + kb + gl * 8;
      ldsld16(gp, (char*)&sm[2 + plane][0] + cc * 1024);
    }
    __syncthreads();
    // --- MFMA: 2 k-steps of 32, hi/lo 3-term product ---
#pragma unroll
    for (int ks = 0; ks < 2; ++ks) {
      short8 Ah[4], Al[4], Bh[4], Bl[4];
#pragma unroll
      for (int ms = 0; ms < 4; ++ms) {
        int off = (mh + ms * 16 + l15) * 64 + (((ks * 4 + quad) ^ (l15 & 7)) * 8);
        Ah[ms] = *(const short8*)&sm[0][off];
        Al[ms] = *(const short8*)&sm[1][off];
      }
#pragma unroll
      for (int ns = 0; ns < 4; ++ns) {
        int off = (nh + ns * 16 + l15) * 64 + (((ks * 4 + quad) ^ (l15 & 7)) * 8);
        Bh[ns] = *(const short8*)&sm[2][off];
        Bl[ns] = *(const short8*)&sm[3][off];
      }
#pragma unroll
      for (int i = 0; i < 4; ++i)
#pragma unroll
        for (int j = 0; j < 4; ++j) {
          floatx4 c = acc[i][j];
          c = __builtin_amdgcn_mfma_f32_16x16x32_bf16(Ah[i], Bh[j], c, 0, 0, 0);
          c = __builtin_amdgcn_mfma_f32_16x16x32_bf16(Ah[i], Bl[j], c, 0, 0, 0);
          c = __builtin_amdgcn_mfma_f32_16x16x32_bf16(Al[i], Bh[j], c, 0, 0, 0);
          acc[i][j] = c;
        }
    }
  }

  // --- epilogue ---
  if (which < 2) {
    unsigned short* O = which == 0 ? Qb : Kb;
#pragma unroll
    for (int i = 0; i < 4; ++i)
#pragma unroll
      for (int j = 0; j < 4; ++j)
#pragma unroll
        for (int r = 0; r < 4; ++r) {
          int m = mh + i * 16 + quad * 4 + r;
          int n = nh + j * 16 + l15;
          O[(size_t)(m0 + m) * DQK + n] = bfr(acc[i][j][r] + biasv[j]);
        }
  } else {
    // V: add bias, split hi/lo, transpose to [d][s] via LDS, store Vt planes
    __syncthreads();
    unsigned short* VH = &sm[0][0];   // 128x128 bf16 (32KB)
    unsigned short* VL = &sm[2][0];
#pragma unroll
    for (int i = 0; i < 4; ++i)
#pragma unroll
      for (int j = 0; j < 4; ++j)
#pragma unroll
        for (int r = 0; r < 4; ++r) {
          int s = mh + i * 16 + quad * 4 + r;
          int d = nh + j * 16 + l15;
          float v = acc[i][j][r] + biasv[j];
          unsigned short h = bfr(v);
          unsigned short lo = bfr(v - bf2f(h));
          int off = d * 128 + (((s >> 3) ^ (d & 15)) * 8) + (s & 7);
          VH[off] = h; VL[off] = lo;
        }
    __syncthreads();
    int b = m0 >> 11, s0 = m0 & 2047;
#pragma unroll
    for (int i = 0; i < 8; ++i) {
      int cch = i * 256 + tid;          // 2048 16B-chunks per plane
      int d = cch >> 4, gI = cch & 15;
      int loff = d * 128 + ((gI ^ (d & 15)) * 8);
      intx4 vh = *(const intx4*)&VH[loff];
      intx4 vl = *(const intx4*)&VL[loff];
      size_t go = ((size_t)b * DQK + d) * SEQ + s0 + gI * 8;
      *(intx4*)&Vth[go] = vh;
      *(intx4*)&Vtl[go] = vl;
    }
  }
}

// ---------------------------------------------------------------------------
// Kernel 2: flash attention, MFMA. q-tile 64 (4 waves x 16 rows), k-tile 64.
// QK^T: Q,K bf16 A-style frags (B^T trick). PV: 3-term hi/lo (Ph*Vh+Pl*Vh+Ph*Vl).
// P C-layout -> A-layout via per-wave LDS strip (stride 80, bank-balanced).
// ---------------------------------------------------------------------------
__global__ __launch_bounds__(256, 2) void attn_kernel(
    const unsigned short* __restrict__ Qb, const unsigned short* __restrict__ Kb,
    const unsigned short* __restrict__ Vth, const unsigned short* __restrict__ Vtl,
    float* __restrict__ Out, GM g, unsigned int t64) {
  __shared__ unsigned short Ks[64 * 128];   // swizzled, 16KB
  __shared__ unsigned short Vh[128 * 64];   // swizzled, 16KB
  __shared__ unsigned short Vl[128 * 64];   // swizzled, 16KB
  __shared__ unsigned short Ph[4][16 * 80]; // per-wave P hi strips
  __shared__ unsigned short Pl[4][16 * 80]; // per-wave P lo strips

  const int tid = threadIdx.x;
  const int w = tid >> 6, lane = tid & 63, l15 = lane & 15, quad = lane >> 4;
  const int b = blockIdx.y, qt = blockIdx.x, qs = qt * 64;

  // Q fragments (A-layout), held in registers for the whole block
  short8 qf[4];
  const unsigned short* Qrow = Qb + ((size_t)(b * SEQ + qs + w * 16 + l15)) * DQK;
#pragma unroll
  for (int j = 0; j < 4; ++j) qf[j] = *(const short8*)&Qrow[j * 32 + quad * 8];

  int rowi[4]; bool growb[4];
#pragma unroll
  for (int r = 0; r < 4; ++r) {
    rowi[r] = qs + w * 16 + quad * 4 + r;
    growb[r] = gbit(g, rowi[r]);
  }

  floatx4 o[8] = {};
  float m_r[4] = {-1e30f, -1e30f, -1e30f, -1e30f};
  float l_r[4] = {0.f, 0.f, 0.f, 0.f};

  const bool qhasg = (t64 >> qt) & 1;
  const unsigned short* KbB = Kb  + (size_t)b * SEQ * DQK;
  const unsigned short* VhB = Vth + (size_t)b * DQK * SEQ;
  const unsigned short* VlB = Vtl + (size_t)b * DQK * SEQ;

  for (int kt = 0; kt < 32; ++kt) {
    const int ks0 = kt * 64;
    if (!((ks0 <= qs + 63) || ((t64 >> kt) & 1) || qhasg)) continue;   // block-uniform

    __syncthreads();   // prior tile's LDS reads complete
    // --- stage K / Vt-hi / Vt-lo (48 x 1KB chunks, swizzled gather) ---
#pragma unroll
    for (int i = 0; i < 12; ++i) {
      int c = w * 12 + i;
      if (c < 16) {
        int F = c * 1024 + lane * 16;
        int r = F >> 8, gs = (F >> 4) & 15, gl = gs ^ (r & 15);
        ldsld16(KbB + (size_t)(ks0 + r) * DQK + gl * 8, (char*)Ks + c * 1024);
      } else if (c < 32) {
        int cc = c - 16;
        int F = cc * 1024 + lane * 16;
        int d = F >> 7, gs = (F >> 4) & 7, gl = gs ^ (d & 7);
        ldsld16(VhB + (size_t)d * SEQ + ks0 + gl * 8, (char*)Vh + cc * 1024);
      } else {
        int cc = c - 32;
        int F = cc * 1024 + lane * 16;
        int d = F >> 7, gs = (F >> 4) & 7, gl = gs ^ (d & 7);
        ldsld16(VlB + (size_t)d * SEQ + ks0 + gl * 8, (char*)Vl + cc * 1024);
      }
    }
    __syncthreads();   // staging visible (compiler drains vmcnt)

    // --- QK^T: S strip [16 q x 64 k] per wave ---
    floatx4 S[4];
#pragma unroll
    for (int c4 = 0; c4 < 4; ++c4) {
      floatx4 s = {0.f, 0.f, 0.f, 0.f};
#pragma unroll
      for (int j = 0; j < 4; ++j) {
        short8 kf = *(const short8*)&Ks[(c4 * 16 + l15) * 128 + (((j * 4 + quad) ^ l15) * 8)];
        s = __builtin_amdgcn_mfma_f32_16x16x32_bf16(qf[j], kf, s, 0, 0, 0);
      }
      S[c4] = s;
    }

    // --- mask + scale + online softmax (rows live in (quad,reg)) ---
    float z[4][4];
    float mx[4] = {-1e30f, -1e30f, -1e30f, -1e30f};
#pragma unroll
    for (int c4 = 0; c4 < 4; ++c4) {
      int col = ks0 + c4 * 16 + l15;
      bool cg = gbit(g, col);
#pragma unroll
      for (int r = 0; r < 4; ++r) {
        bool ok = (col <= rowi[r]) || cg || growb[r];
        float zz = ok ? S[c4][r] * INV_SCALE : -1e30f;
        z[c4][r] = zz;
        mx[r] = fmaxf(mx[r], zz);
      }
    }
#pragma unroll
    for (int d = 1; d < 16; d <<= 1)
#pragma unroll
      for (int r = 0; r < 4; ++r) mx[r] = fmaxf(mx[r], __shfl_xor(mx[r], d));
    float alpha[4], rs[4] = {0.f, 0.f, 0.f, 0.f};
#pragma unroll
    for (int r = 0; r < 4; ++r) {
      float mn = fmaxf(m_r[r], mx[r]);
      alpha[r] = __expf(m_r[r] - mn);
      m_r[r] = mn;
    }
    float p[4][4];
#pragma unroll
    for (int c4 = 0; c4 < 4; ++c4)
#pragma unroll
      for (int r = 0; r < 4; ++r) {
        float pp = __expf(z[c4][r] - m_r[r]);
        p[c4][r] = pp;
        rs[r] += pp;
      }
#pragma unroll
    for (int d = 1; d < 16; d <<= 1)
#pragma unroll
      for (int r = 0; r < 4; ++r) rs[r] += __shfl_xor(rs[r], d);
#pragma unroll
    for (int r = 0; r < 4; ++r) l_r[r] = l_r[r] * alpha[r] + rs[r];
#pragma unroll
    for (int n = 0; n < 8; ++n)
#pragma unroll
      for (int r = 0; r < 4; ++r) o[n][r] *= alpha[r];

    // --- P (C-layout) -> per-wave LDS strip as hi/lo bf16 ---
#pragma unroll
    for (int c4 = 0; c4 < 4; ++c4)
#pragma unroll
      for (int r = 0; r < 4; ++r) {
        unsigned short h = bfr(p[c4][r]);
        unsigned short lo = bfr(p[c4][r] - bf2f(h));
        int off = (quad * 4 + r) * 80 + c4 * 16 + l15;
        Ph[w][off] = h; Pl[w][off] = lo;
      }
    short8 pf[2], pg[2];
#pragma unroll
    for (int kq = 0; kq < 2; ++kq) {
      int off = l15 * 80 + kq * 32 + quad * 8;
      pf[kq] = *(const short8*)&Ph[w][off];
      pg[kq] = *(const short8*)&Pl[w][off];
    }

    // --- PV: O[16 x 128] += P @ V (3-term hi/lo) ---
#pragma unroll
    for (int n = 0; n < 8; ++n) {
      int drow = n * 16 + l15;
#pragma unroll
      for (int kq = 0; kq < 2; ++kq) {
        int off = drow * 64 + (((kq * 4 + quad) ^ (drow & 7)) * 8);
        short8 vhf = *(const short8*)&Vh[off];
        short8 vlf = *(const short8*)&Vl[off];
        floatx4 c = o[n];
        c = __builtin_amdgcn_mfma_f32_16x16x32_bf16(pf[kq], vhf, c, 0, 0, 0);
        c = __builtin_amdgcn_mfma_f32_16x16x32_bf16(pg[kq], vhf, c, 0, 0, 0);
        c = __builtin_amdgcn_mfma_f32_16x16x32_bf16(pf[kq], vlf, c, 0, 0, 0);
        o[n] = c;
      }
    }
  }

  // --- epilogue: normalize and store fp32 ---
  float invl[4];
#pragma unroll
  for (int r = 0; r < 4; ++r) invl[r] = 1.0f / l_r[r];
  float* Ob = Out + (size_t)b * SEQ * DQK;
#pragma unroll
  for (int n = 0; n < 8; ++n)
#pragma unroll
    for (int r = 0; r < 4; ++r)
      Ob[(size_t)(qs + w * 16 + quad * 4 + r) * DQK + n * 16 + l15] = o[n][r] * invl[r];
}

// ---------------------------------------------------------------------------
extern "C" void kernel_launch(void* const* d_in, const int* in_sizes, int n_in,
                              void* d_out, int out_size, void* d_ws, size_t ws_size,
                              hipStream_t stream) {
  const float* q  = (const float*)d_in[0];
  const float* k  = (const float*)d_in[1];
  const float* v  = (const float*)d_in[2];
  const float* Wq = (const float*)d_in[3];
  const float* bq = (const float*)d_in[4];
  const float* Wk = (const float*)d_in[5];
  const float* bk = (const float*)d_in[6];
  const float* Wv = (const float*)d_in[7];
  const float* bv = (const float*)d_in[8];
  float* out = (float*)d_out;

  unsigned short* Qb  = (unsigned short*)d_ws;                 // 4MB bf16 [s][d]
  unsigned short* Kb2 = Qb  + (size_t)MTOT * DQK;              // 4MB
  unsigned short* Vth = Kb2 + (size_t)MTOT * DQK;              // 4MB  [b][d][s]
  unsigned short* Vtl = Vth + (size_t)MTOT * DQK;              // 4MB
  unsigned short* Whi = Vtl + (size_t)MTOT * DQK;              // 768KB
  unsigned short* Wlo = Whi + (size_t)3 * DQK * DIN;           // 768KB

  GM g;
  compute_gtok(g.w);
  unsigned int t64 = 0;
  for (int t = 0; t < 32; ++t) if (g.w[t] != 0ULL) t64 |= (1u << t);

  hipLaunchKernelGGL(wconv_kernel, dim3(128, 3), dim3(256), 0, stream,
                     Wq, Wk, Wv, Whi, Wlo);
  hipLaunchKernelGGL(proj_kernel, dim3(128, 3), dim3(256), 0, stream,
                     q, k, v, Whi, Wlo, bq, bk, bv, Qb, Kb2, Vth, Vtl);
  hipLaunchKernelGGL(attn_kernel, dim3(32, 8), dim3(256), 0, stream,
                     Qb, Kb2, Vth, Vtl, out, g, t64);
}

// Round 3
// 293.466 us; speedup vs baseline: 3.0361x; 1.1019x over previous
//
#include <hip/hip_runtime.h>
#include <cstdint>

constexpr int SEQ  = 2048;
constexpr int DIN  = 1024;
constexpr int DQK  = 128;
constexpr int NB   = 8;
constexpr int MTOT = NB * SEQ;   // 16384
constexpr float INV_SCALE = 0.08838834764831845f;  // 1/sqrt(128)

typedef __attribute__((ext_vector_type(8))) short  short8;
typedef __attribute__((ext_vector_type(4))) float  floatx4;
typedef __attribute__((ext_vector_type(4))) int    intx4;

struct GM { unsigned long long w[32]; };   // 2048-bit global-token mask

// ---------------------------------------------------------------------------
// Host-side reproduction of np.random.default_rng(0).choice(2048, 32, False).
// (verified correct in Round 1: absmax 9.8e-4)
// ---------------------------------------------------------------------------
static void compute_gtok(unsigned long long bits[32]) {
  typedef unsigned __int128 u128;
  uint32_t pool[4];
  uint32_t hc = 0x43b0d7e5u;
  auto hashmix = [&hc](uint32_t v) -> uint32_t {
    v ^= hc; hc *= 0x931e8875u; v *= hc; v ^= v >> 16; return v;
  };
  auto mixf = [](uint32_t x, uint32_t y) -> uint32_t {
    uint32_t r = x * 0xca01f9ddu - y * 0x4973f715u;
    r ^= r >> 16; return r;
  };
  pool[0] = hashmix(0u);
  for (int i = 1; i < 4; ++i) pool[i] = hashmix(0u);
  for (int s = 0; s < 4; ++s)
    for (int d = 0; d < 4; ++d)
      if (s != d) pool[d] = mixf(pool[d], hashmix(pool[s]));
  uint32_t hb = 0x8b51f9ddu;
  uint32_t st[8];
  for (int i = 0; i < 8; ++i) {
    uint32_t dv = pool[i & 3];
    dv ^= hb; hb *= 0x58f38dedu; dv *= hb; dv ^= dv >> 16;
    st[i] = dv;
  }
  uint64_t sv[4];
  for (int i = 0; i < 4; ++i)
    sv[i] = (uint64_t)st[2 * i] | ((uint64_t)st[2 * i + 1] << 32);
  const u128 MUL = ((u128)2549297995355413924ULL << 64) | (u128)4865540595714422341ULL;
  u128 initstate = ((u128)sv[0] << 64) | sv[1];
  u128 initseq   = ((u128)sv[2] << 64) | sv[3];
  u128 state = 0;
  u128 inc = (initseq << 1) | 1;
  state = state * MUL + inc;
  state += initstate;
  state = state * MUL + inc;
  bool has32 = false; uint32_t cache32 = 0;
  auto next64 = [&]() -> uint64_t {
    state = state * MUL + inc;
    uint64_t hi = (uint64_t)(state >> 64);
    uint64_t lo = (uint64_t)state;
    unsigned rot = (unsigned)(state >> 122);
    uint64_t x = hi ^ lo;
    return (x >> rot) | (x << ((64u - rot) & 63u));
  };
  auto next32 = [&]() -> uint32_t {
    if (has32) { has32 = false; return cache32; }
    uint64_t n = next64();
    has32 = true; cache32 = (uint32_t)(n >> 32);
    return (uint32_t)n;
  };
  bool in_set[SEQ];
  for (int i = 0; i < SEQ; ++i) in_set[i] = false;
  for (uint32_t j = 2016; j < 2048; ++j) {
    uint32_t rng_excl = j + 1;
    uint64_t m = (uint64_t)next32() * rng_excl;
    uint32_t leftover = (uint32_t)m;
    if (leftover < rng_excl) {
      uint32_t threshold = (0xFFFFFFFFu - j) % rng_excl;
      while (leftover < threshold) {
        m = (uint64_t)next32() * rng_excl;
        leftover = (uint32_t)m;
      }
    }
    uint32_t val = (uint32_t)(m >> 32);
    if (in_set[val]) in_set[j] = true;
    else in_set[val] = true;
  }
  for (int i = 0; i < 32; ++i) bits[i] = 0ULL;
  for (int t = 0; t < SEQ; ++t)
    if (in_set[t]) bits[t >> 6] |= (1ULL << (t & 63));
}

// ---------------------------------------------------------------------------
// helpers: trunc-hi split (hi = RTZ bf16, lo = RTZ bf16 of residual).
// Combined representation error <= 2^-16 relative; 3-term MFMA covers it.
// v_perm_b32 packs two hi16s in one instruction.
// ---------------------------------------------------------------------------
__device__ __forceinline__ float bf2f(unsigned short h) {
  return __uint_as_float(((unsigned)h) << 16);
}
__device__ __forceinline__ void ldsld16(const void* g, void* l) {
  __builtin_amdgcn_global_load_lds(
      (const __attribute__((address_space(1))) unsigned int*)g,
      (__attribute__((address_space(3))) unsigned int*)l, 16, 0, 0);
}
__device__ __forceinline__ bool gbit(const GM& g, int j) {
  return (g.w[j >> 6] >> (j & 63)) & 1ULL;
}
// split float4 -> packed hi pair-words and lo pair-words
__device__ __forceinline__ void split4(float4 x, unsigned hw[2], unsigned lw[2]) {
  unsigned u0 = __float_as_uint(x.x), u1 = __float_as_uint(x.y);
  unsigned u2 = __float_as_uint(x.z), u3 = __float_as_uint(x.w);
  hw[0] = __builtin_amdgcn_perm(u1, u0, 0x07060302u);
  hw[1] = __builtin_amdgcn_perm(u3, u2, 0x07060302u);
  unsigned r0 = __float_as_uint(x.x - __uint_as_float(u0 & 0xFFFF0000u));
  unsigned r1 = __float_as_uint(x.y - __uint_as_float(u1 & 0xFFFF0000u));
  unsigned r2 = __float_as_uint(x.z - __uint_as_float(u2 & 0xFFFF0000u));
  unsigned r3 = __float_as_uint(x.w - __uint_as_float(u3 & 0xFFFF0000u));
  lw[0] = __builtin_amdgcn_perm(r1, r0, 0x07060302u);
  lw[1] = __builtin_amdgcn_perm(r3, r2, 0x07060302u);
}
__device__ __forceinline__ void split1(float v, unsigned short& h, unsigned short& l) {
  unsigned u = __float_as_uint(v);
  h = (unsigned short)(u >> 16);
  float rr = v - __uint_as_float(u & 0xFFFF0000u);
  l = (unsigned short)(__float_as_uint(rr) >> 16);
}

// ---------------------------------------------------------------------------
// Kernel 0: convert W (3 x [128][1024] fp32) to hi/lo bf16 planes (flat).
// ---------------------------------------------------------------------------
__global__ __launch_bounds__(256) void wconv_kernel(
    const float* __restrict__ Wq, const float* __restrict__ Wk, const float* __restrict__ Wv,
    unsigned short* __restrict__ Whi, unsigned short* __restrict__ Wlo) {
  const float* W = blockIdx.y == 0 ? Wq : blockIdx.y == 1 ? Wk : Wv;
  size_t base = (size_t)blockIdx.y * DQK * DIN;
  int e = (blockIdx.x * 256 + threadIdx.x) * 4;
  float4 x = *(const float4*)&W[e];
  unsigned hw[2], lw[2];
  split4(x, hw, lw);
  *(uint2*)&Whi[base + e] = make_uint2(hw[0], hw[1]);
  *(uint2*)&Wlo[base + e] = make_uint2(lw[0], lw[1]);
}

// ---------------------------------------------------------------------------
// Kernel 1: projections via bf16 MFMA with hi/lo split (fp32-accurate).
// 128x128 block tile, 4 waves of 64x64 (4x4 of 16x16x32), K-chunk 64.
// which 0/1 -> Q/K bf16 [s][d]; which 2 -> Vt hi/lo bf16 [b][d][s].
// ---------------------------------------------------------------------------
__global__ __launch_bounds__(256, 2) void proj_kernel(
    const float* __restrict__ xq, const float* __restrict__ xk, const float* __restrict__ xv,
    const unsigned short* __restrict__ Whi, const unsigned short* __restrict__ Wlo,
    const float* __restrict__ bq, const float* __restrict__ bk, const float* __restrict__ bv,
    unsigned short* __restrict__ Qb, unsigned short* __restrict__ Kb,
    unsigned short* __restrict__ Vth, unsigned short* __restrict__ Vtl) {
  const int which = blockIdx.y;
  const float* X    = which == 0 ? xq : which == 1 ? xk : xv;
  const float* bias = which == 0 ? bq : which == 1 ? bk : bv;
  const int m0 = blockIdx.x * 128;

  __shared__ unsigned short sm[4][8192];  // Xhi, Xlo, Whi, Wlo tiles [128][64]

  const int tid = threadIdx.x;
  const int w = tid >> 6, lane = tid & 63, l15 = lane & 15, quad = lane >> 4;
  const int mh = (w >> 1) * 64, nh = (w & 1) * 64;

  floatx4 acc[4][4] = {};
  float biasv[4];
#pragma unroll
  for (int j = 0; j < 4; ++j) biasv[j] = bias[nh + j * 16 + l15];

  const unsigned short* WhiP = Whi + (size_t)which * DQK * DIN;
  const unsigned short* WloP = Wlo + (size_t)which * DQK * DIN;

  for (int kb = 0; kb < DIN; kb += 64) {
    __syncthreads();
    // --- stage X: fp32 -> hi/lo bf16 planes (trunc+perm), swizzled ---
#pragma unroll
    for (int i = 0; i < 8; ++i) {
      int f = tid + i * 256;
      int r = f >> 4, c4 = f & 15;
      float4 x = *(const float4*)&X[(size_t)(m0 + r) * DIN + kb + c4 * 4];
      unsigned hw[2], lw[2];
      split4(x, hw, lw);
      int off = r * 64 + (((c4 >> 1) ^ (r & 7)) * 8) + (c4 & 1) * 4;
      *(uint2*)&sm[0][off] = make_uint2(hw[0], hw[1]);
      *(uint2*)&sm[1][off] = make_uint2(lw[0], lw[1]);
    }
    // --- stage W hi/lo planes via global_load_lds (gather applies swizzle) ---
#pragma unroll
    for (int i = 0; i < 8; ++i) {
      int c = w * 8 + i;                 // 0..31: plane = c>>4, chunk cc = c&15
      int plane = c >> 4, cc = c & 15;
      int F = cc * 1024 + lane * 16;     // byte in 16KB plane tile
      int n = F >> 7, gs = (F >> 4) & 7, gl = gs ^ (n & 7);
      const unsigned short* gp = (plane ? WloP : WhiP) + (size_t)n * DIN + kb + gl * 8;
      ldsld16(gp, (char*)&sm[2 + plane][0] + cc * 1024);
    }
    __syncthreads();
    // --- MFMA: 2 k-steps of 32, hi/lo 3-term product ---
#pragma unroll
    for (int ks = 0; ks < 2; ++ks) {
      short8 Ah[4], Al[4], Bh[4], Bl[4];
#pragma unroll
      for (int ms = 0; ms < 4; ++ms) {
        int off = (mh + ms * 16 + l15) * 64 + (((ks * 4 + quad) ^ (l15 & 7)) * 8);
        Ah[ms] = *(const short8*)&sm[0][off];
        Al[ms] = *(const short8*)&sm[1][off];
      }
#pragma unroll
      for (int ns = 0; ns < 4; ++ns) {
        int off = (nh + ns * 16 + l15) * 64 + (((ks * 4 + quad) ^ (l15 & 7)) * 8);
        Bh[ns] = *(const short8*)&sm[2][off];
        Bl[ns] = *(const short8*)&sm[3][off];
      }
#pragma unroll
      for (int i = 0; i < 4; ++i)
#pragma unroll
        for (int j = 0; j < 4; ++j) {
          floatx4 c = acc[i][j];
          c = __builtin_amdgcn_mfma_f32_16x16x32_bf16(Ah[i], Bh[j], c, 0, 0, 0);
          c = __builtin_amdgcn_mfma_f32_16x16x32_bf16(Ah[i], Bl[j], c, 0, 0, 0);
          c = __builtin_amdgcn_mfma_f32_16x16x32_bf16(Al[i], Bh[j], c, 0, 0, 0);
          acc[i][j] = c;
        }
    }
  }

  // --- epilogue ---
  if (which < 2) {
    unsigned short* O = which == 0 ? Qb : Kb;
#pragma unroll
    for (int i = 0; i < 4; ++i)
#pragma unroll
      for (int j = 0; j < 4; ++j)
#pragma unroll
        for (int r = 0; r < 4; ++r) {
          int m = mh + i * 16 + quad * 4 + r;
          int n = nh + j * 16 + l15;
          float v = acc[i][j][r] + biasv[j];
          O[(size_t)(m0 + m) * DQK + n] =
              (unsigned short)((__float_as_uint(v) + 0x7FFFu +
                                ((__float_as_uint(v) >> 16) & 1u)) >> 16);  // RNE single
        }
  } else {
    // V: add bias, split hi/lo, transpose to [d][s] via LDS, store Vt planes
    __syncthreads();
    unsigned short* VH = &sm[0][0];   // 128x128 bf16 (32KB)
    unsigned short* VL = &sm[2][0];
#pragma unroll
    for (int i = 0; i < 4; ++i)
#pragma unroll
      for (int j = 0; j < 4; ++j)
#pragma unroll
        for (int r = 0; r < 4; ++r) {
          int s = mh + i * 16 + quad * 4 + r;
          int d = nh + j * 16 + l15;
          float v = acc[i][j][r] + biasv[j];
          unsigned short h, lo;
          split1(v, h, lo);
          int off = d * 128 + (((s >> 3) ^ (d & 15)) * 8) + (s & 7);
          VH[off] = h; VL[off] = lo;
        }
    __syncthreads();
    int b = m0 >> 11, s0 = m0 & 2047;
#pragma unroll
    for (int i = 0; i < 8; ++i) {
      int cch = i * 256 + tid;          // 2048 16B-chunks per plane
      int d = cch >> 4, gI = cch & 15;
      int loff = d * 128 + ((gI ^ (d & 15)) * 8);
      intx4 vh = *(const intx4*)&VH[loff];
      intx4 vl = *(const intx4*)&VL[loff];
      size_t go = ((size_t)b * DQK + d) * SEQ + s0 + gI * 8;
      *(intx4*)&Vth[go] = vh;
      *(intx4*)&Vtl[go] = vl;
    }
  }
}

// ---------------------------------------------------------------------------
// Kernel 2: flash attention, MFMA, 2-way split-KV (parity interleaved).
// grid.x = 64 (qt = x>>1, half = x&1), grid.y = batch -> 512 blocks
// => 2 blocks/CU resident (68.5KB LDS), 2 waves/SIMD for latency hiding.
// Writes UNNORMALIZED partial O + (m,l) per row; merge_kernel combines.
// ---------------------------------------------------------------------------
__global__ __launch_bounds__(256, 2) void attn_kernel(
    const unsigned short* __restrict__ Qb, const unsigned short* __restrict__ Kb,
    const unsigned short* __restrict__ Vth, const unsigned short* __restrict__ Vtl,
    float* __restrict__ Opart, float2* __restrict__ ML, GM g, unsigned int t64) {
  __shared__ unsigned short Ks[64 * 128];   // swizzled, 16KB
  __shared__ unsigned short Vh[128 * 64];   // swizzled, 16KB
  __shared__ unsigned short Vl[128 * 64];   // swizzled, 16KB
  __shared__ unsigned short Ph[4][16 * 80]; // per-wave P hi strips
  __shared__ unsigned short Pl[4][16 * 80]; // per-wave P lo strips

  const int tid = threadIdx.x;
  const int w = tid >> 6, lane = tid & 63, l15 = lane & 15, quad = lane >> 4;
  const int b = blockIdx.y;
  const int qt = blockIdx.x >> 1, half = blockIdx.x & 1;
  const int qs = qt * 64;

  // Q fragments (A-layout), held in registers for the whole block
  short8 qf[4];
  const unsigned short* Qrow = Qb + ((size_t)(b * SEQ + qs + w * 16 + l15)) * DQK;
#pragma unroll
  for (int j = 0; j < 4; ++j) qf[j] = *(const short8*)&Qrow[j * 32 + quad * 8];

  int rowi[4]; bool growb[4];
#pragma unroll
  for (int r = 0; r < 4; ++r) {
    rowi[r] = qs + w * 16 + quad * 4 + r;
    growb[r] = gbit(g, rowi[r]);
  }

  floatx4 o[8] = {};
  float m_r[4] = {-1e30f, -1e30f, -1e30f, -1e30f};
  float l_r[4] = {0.f, 0.f, 0.f, 0.f};

  const bool qhasg = (t64 >> qt) & 1;
  const unsigned short* KbB = Kb  + (size_t)b * SEQ * DQK;
  const unsigned short* VhB = Vth + (size_t)b * DQK * SEQ;
  const unsigned short* VlB = Vtl + (size_t)b * DQK * SEQ;

  for (int kt = half; kt < 32; kt += 2) {    // parity-interleaved split-KV
    const int ks0 = kt * 64;
    if (!((ks0 <= qs + 63) || ((t64 >> kt) & 1) || qhasg)) continue;   // block-uniform

    __syncthreads();   // prior tile's LDS reads complete
    // --- stage K / Vt-hi / Vt-lo (48 x 1KB chunks, swizzled gather) ---
#pragma unroll
    for (int i = 0; i < 12; ++i) {
      int c = w * 12 + i;
      if (c < 16) {
        int F = c * 1024 + lane * 16;
        int r = F >> 8, gs = (F >> 4) & 15, gl = gs ^ (r & 15);
        ldsld16(KbB + (size_t)(ks0 + r) * DQK + gl * 8, (char*)Ks + c * 1024);
      } else if (c < 32) {
        int cc = c - 16;
        int F = cc * 1024 + lane * 16;
        int d = F >> 7, gs = (F >> 4) & 7, gl = gs ^ (d & 7);
        ldsld16(VhB + (size_t)d * SEQ + ks0 + gl * 8, (char*)Vh + cc * 1024);
      } else {
        int cc = c - 32;
        int F = cc * 1024 + lane * 16;
        int d = F >> 7, gs = (F >> 4) & 7, gl = gs ^ (d & 7);
        ldsld16(VlB + (size_t)d * SEQ + ks0 + gl * 8, (char*)Vl + cc * 1024);
      }
    }
    __syncthreads();   // staging visible

    // --- QK^T: S strip [16 q x 64 k] per wave ---
    floatx4 S[4];
#pragma unroll
    for (int c4 = 0; c4 < 4; ++c4) {
      floatx4 s = {0.f, 0.f, 0.f, 0.f};
#pragma unroll
      for (int j = 0; j < 4; ++j) {
        short8 kf = *(const short8*)&Ks[(c4 * 16 + l15) * 128 + (((j * 4 + quad) ^ l15) * 8)];
        s = __builtin_amdgcn_mfma_f32_16x16x32_bf16(qf[j], kf, s, 0, 0, 0);
      }
      S[c4] = s;
    }

    // --- mask + scale + online softmax ---
    float z[4][4];
    float mx[4] = {-1e30f, -1e30f, -1e30f, -1e30f};
#pragma unroll
    for (int c4 = 0; c4 < 4; ++c4) {
      int col = ks0 + c4 * 16 + l15;
      bool cg = gbit(g, col);
#pragma unroll
      for (int r = 0; r < 4; ++r) {
        bool ok = (col <= rowi[r]) || cg || growb[r];
        float zz = ok ? S[c4][r] * INV_SCALE : -1e30f;
        z[c4][r] = zz;
        mx[r] = fmaxf(mx[r], zz);
      }
    }
#pragma unroll
    for (int d = 1; d < 16; d <<= 1)
#pragma unroll
      for (int r = 0; r < 4; ++r) mx[r] = fmaxf(mx[r], __shfl_xor(mx[r], d));
    float alpha[4], rs[4] = {0.f, 0.f, 0.f, 0.f};
#pragma unroll
    for (int r = 0; r < 4; ++r) {
      float mn = fmaxf(m_r[r], mx[r]);
      alpha[r] = __expf(m_r[r] - mn);
      m_r[r] = mn;
    }
    float p[4][4];
#pragma unroll
    for (int c4 = 0; c4 < 4; ++c4)
#pragma unroll
      for (int r = 0; r < 4; ++r) {
        float pp = __expf(z[c4][r] - m_r[r]);
        p[c4][r] = pp;
        rs[r] += pp;
      }
#pragma unroll
    for (int d = 1; d < 16; d <<= 1)
#pragma unroll
      for (int r = 0; r < 4; ++r) rs[r] += __shfl_xor(rs[r], d);
#pragma unroll
    for (int r = 0; r < 4; ++r) l_r[r] = l_r[r] * alpha[r] + rs[r];
#pragma unroll
    for (int n = 0; n < 8; ++n)
#pragma unroll
      for (int r = 0; r < 4; ++r) o[n][r] *= alpha[r];

    // --- P (C-layout) -> per-wave LDS strip as hi/lo bf16 (trunc split) ---
#pragma unroll
    for (int c4 = 0; c4 < 4; ++c4)
#pragma unroll
      for (int r = 0; r < 4; ++r) {
        unsigned short h, lo;
        split1(p[c4][r], h, lo);
        int off = (quad * 4 + r) * 80 + c4 * 16 + l15;
        Ph[w][off] = h; Pl[w][off] = lo;
      }
    short8 pf[2], pg[2];
#pragma unroll
    for (int kq = 0; kq < 2; ++kq) {
      int off = l15 * 80 + kq * 32 + quad * 8;
      pf[kq] = *(const short8*)&Ph[w][off];
      pg[kq] = *(const short8*)&Pl[w][off];
    }

    // --- PV: O[16 x 128] += P @ V (3-term hi/lo) ---
#pragma unroll
    for (int n = 0; n < 8; ++n) {
      int drow = n * 16 + l15;
#pragma unroll
      for (int kq = 0; kq < 2; ++kq) {
        int off = drow * 64 + (((kq * 4 + quad) ^ (drow & 7)) * 8);
        short8 vhf = *(const short8*)&Vh[off];
        short8 vlf = *(const short8*)&Vl[off];
        floatx4 c = o[n];
        c = __builtin_amdgcn_mfma_f32_16x16x32_bf16(pf[kq], vhf, c, 0, 0, 0);
        c = __builtin_amdgcn_mfma_f32_16x16x32_bf16(pg[kq], vhf, c, 0, 0, 0);
        c = __builtin_amdgcn_mfma_f32_16x16x32_bf16(pf[kq], vlf, c, 0, 0, 0);
        o[n] = c;
      }
    }
  }

  // --- epilogue: write UNNORMALIZED partial + (m,l) ---
  const size_t grp = (size_t)(b * 32 + qt) * 2 + half;
  float* Op = Opart + grp * 64 * 128;
#pragma unroll
  for (int n = 0; n < 8; ++n)
#pragma unroll
    for (int r = 0; r < 4; ++r)
      Op[(w * 16 + quad * 4 + r) * 128 + n * 16 + l15] = o[n][r];
  if (l15 == 0) {
#pragma unroll
    for (int r = 0; r < 4; ++r)
      ML[grp * 64 + w * 16 + quad * 4 + r] = make_float2(m_r[r], l_r[r]);
  }
}

// ---------------------------------------------------------------------------
// Kernel 3: merge the two split-KV partials.
// out = (w0*O0 + w1*O1) / (w0*l0 + w1*l1),  wi = exp(mi - max(m0,m1)).
// An empty half has m=-1e30, l=0, O=0 -> wi==0, contributes nothing.
// ---------------------------------------------------------------------------
__global__ __launch_bounds__(256) void merge_kernel(
    const float* __restrict__ Opart, const float2* __restrict__ ML,
    float* __restrict__ Out) {
  const int t = threadIdx.x;
  const int row = blockIdx.x * 2 + (t >> 7);   // 0..16383
  const int col = t & 127;
  const int grp = row >> 6;                    // b*32 + qt
  const int rin = row & 63;
  const size_t i0 = ((size_t)grp * 2 + 0) * 64 + rin;
  const size_t i1 = ((size_t)grp * 2 + 1) * 64 + rin;
  const float2 ml0 = ML[i0], ml1 = ML[i1];
  const float m = fmaxf(ml0.x, ml1.x);
  const float w0 = __expf(ml0.x - m), w1 = __expf(ml1.x - m);
  const float denom = w0 * ml0.y + w1 * ml1.y;
  const float o0 = Opart[i0 * 128 + col], o1 = Opart[i1 * 128 + col];
  Out[(size_t)row * 128 + col] = (w0 * o0 + w1 * o1) / denom;
}

// ---------------------------------------------------------------------------
extern "C" void kernel_launch(void* const* d_in, const int* in_sizes, int n_in,
                              void* d_out, int out_size, void* d_ws, size_t ws_size,
                              hipStream_t stream) {
  const float* q  = (const float*)d_in[0];
  const float* k  = (const float*)d_in[1];
  const float* v  = (const float*)d_in[2];
  const float* Wq = (const float*)d_in[3];
  const float* bq = (const float*)d_in[4];
  const float* Wk = (const float*)d_in[5];
  const float* bk = (const float*)d_in[6];
  const float* Wv = (const float*)d_in[7];
  const float* bv = (const float*)d_in[8];
  float* out = (float*)d_out;

  unsigned short* Qb  = (unsigned short*)d_ws;                 // 4MB bf16 [s][d]
  unsigned short* Kb2 = Qb  + (size_t)MTOT * DQK;              // 4MB
  unsigned short* Vth = Kb2 + (size_t)MTOT * DQK;              // 4MB  [b][d][s]
  unsigned short* Vtl = Vth + (size_t)MTOT * DQK;              // 4MB
  unsigned short* Whi = Vtl + (size_t)MTOT * DQK;              // 768KB
  unsigned short* Wlo = Whi + (size_t)3 * DQK * DIN;           // 768KB
  float*  Opart = (float*)(Wlo + (size_t)3 * DQK * DIN);       // 16MB partials
  float2* ML    = (float2*)(Opart + (size_t)2 * MTOT * DQK);   // 256KB (m,l)

  GM g;
  compute_gtok(g.w);
  unsigned int t64 = 0;
  for (int t = 0; t < 32; ++t) if (g.w[t] != 0ULL) t64 |= (1u << t);

  hipLaunchKernelGGL(wconv_kernel, dim3(128, 3), dim3(256), 0, stream,
                     Wq, Wk, Wv, Whi, Wlo);
  hipLaunchKernelGGL(proj_kernel, dim3(128, 3), dim3(256), 0, stream,
                     q, k, v, Whi, Wlo, bq, bk, bv, Qb, Kb2, Vth, Vtl);
  hipLaunchKernelGGL(attn_kernel, dim3(64, 8), dim3(256), 0, stream,
                     Qb, Kb2, Vth, Vtl, Opart, ML, g, t64);
  hipLaunchKernelGGL(merge_kernel, dim3(MTOT / 2), dim3(256), 0, stream,
                     Opart, ML, out);
}

// Round 4
// 279.982 us; speedup vs baseline: 3.1824x; 1.0482x over previous
//
#include <hip/hip_runtime.h>
#include <cstdint>

constexpr int SEQ  = 2048;
constexpr int DIN  = 1024;
constexpr int DQK  = 128;
constexpr int NB   = 8;
constexpr int MTOT = NB * SEQ;   // 16384
constexpr float INV_SCALE = 0.08838834764831845f;  // 1/sqrt(128)

typedef __attribute__((ext_vector_type(8))) short  short8;
typedef __attribute__((ext_vector_type(4))) float  floatx4;
typedef __attribute__((ext_vector_type(4))) int    intx4;

struct GM { unsigned long long w[32]; };   // 2048-bit global-token mask

// ---------------------------------------------------------------------------
// Host-side reproduction of np.random.default_rng(0).choice(2048, 32, False).
// (verified correct since Round 1)
// ---------------------------------------------------------------------------
static void compute_gtok(unsigned long long bits[32]) {
  typedef unsigned __int128 u128;
  uint32_t pool[4];
  uint32_t hc = 0x43b0d7e5u;
  auto hashmix = [&hc](uint32_t v) -> uint32_t {
    v ^= hc; hc *= 0x931e8875u; v *= hc; v ^= v >> 16; return v;
  };
  auto mixf = [](uint32_t x, uint32_t y) -> uint32_t {
    uint32_t r = x * 0xca01f9ddu - y * 0x4973f715u;
    r ^= r >> 16; return r;
  };
  pool[0] = hashmix(0u);
  for (int i = 1; i < 4; ++i) pool[i] = hashmix(0u);
  for (int s = 0; s < 4; ++s)
    for (int d = 0; d < 4; ++d)
      if (s != d) pool[d] = mixf(pool[d], hashmix(pool[s]));
  uint32_t hb = 0x8b51f9ddu;
  uint32_t st[8];
  for (int i = 0; i < 8; ++i) {
    uint32_t dv = pool[i & 3];
    dv ^= hb; hb *= 0x58f38dedu; dv *= hb; dv ^= dv >> 16;
    st[i] = dv;
  }
  uint64_t sv[4];
  for (int i = 0; i < 4; ++i)
    sv[i] = (uint64_t)st[2 * i] | ((uint64_t)st[2 * i + 1] << 32);
  const u128 MUL = ((u128)2549297995355413924ULL << 64) | (u128)4865540595714422341ULL;
  u128 initstate = ((u128)sv[0] << 64) | sv[1];
  u128 initseq   = ((u128)sv[2] << 64) | sv[3];
  u128 state = 0;
  u128 inc = (initseq << 1) | 1;
  state = state * MUL + inc;
  state += initstate;
  state = state * MUL + inc;
  bool has32 = false; uint32_t cache32 = 0;
  auto next64 = [&]() -> uint64_t {
    state = state * MUL + inc;
    uint64_t hi = (uint64_t)(state >> 64);
    uint64_t lo = (uint64_t)state;
    unsigned rot = (unsigned)(state >> 122);
    uint64_t x = hi ^ lo;
    return (x >> rot) | (x << ((64u - rot) & 63u));
  };
  auto next32 = [&]() -> uint32_t {
    if (has32) { has32 = false; return cache32; }
    uint64_t n = next64();
    has32 = true; cache32 = (uint32_t)(n >> 32);
    return (uint32_t)n;
  };
  bool in_set[SEQ];
  for (int i = 0; i < SEQ; ++i) in_set[i] = false;
  for (uint32_t j = 2016; j < 2048; ++j) {
    uint32_t rng_excl = j + 1;
    uint64_t m = (uint64_t)next32() * rng_excl;
    uint32_t leftover = (uint32_t)m;
    if (leftover < rng_excl) {
      uint32_t threshold = (0xFFFFFFFFu - j) % rng_excl;
      while (leftover < threshold) {
        m = (uint64_t)next32() * rng_excl;
        leftover = (uint32_t)m;
      }
    }
    uint32_t val = (uint32_t)(m >> 32);
    if (in_set[val]) in_set[j] = true;
    else in_set[val] = true;
  }
  for (int i = 0; i < 32; ++i) bits[i] = 0ULL;
  for (int t = 0; t < SEQ; ++t)
    if (in_set[t]) bits[t >> 6] |= (1ULL << (t & 63));
}

// ---------------------------------------------------------------------------
// helpers
// ---------------------------------------------------------------------------
__device__ __forceinline__ void ldsld16(const void* g, void* l) {
  __builtin_amdgcn_global_load_lds(
      (const __attribute__((address_space(1))) unsigned int*)g,
      (__attribute__((address_space(3))) unsigned int*)l, 16, 0, 0);
}
__device__ __forceinline__ bool gbit(const GM& g, int j) {
  return (g.w[j >> 6] >> (j & 63)) & 1ULL;
}
// trunc-hi split: hi = RTZ bf16, lo = RTZ bf16 of residual (covered by 3-term)
__device__ __forceinline__ void split4(float4 x, unsigned hw[2], unsigned lw[2]) {
  unsigned u0 = __float_as_uint(x.x), u1 = __float_as_uint(x.y);
  unsigned u2 = __float_as_uint(x.z), u3 = __float_as_uint(x.w);
  hw[0] = __builtin_amdgcn_perm(u1, u0, 0x07060302u);
  hw[1] = __builtin_amdgcn_perm(u3, u2, 0x07060302u);
  unsigned r0 = __float_as_uint(x.x - __uint_as_float(u0 & 0xFFFF0000u));
  unsigned r1 = __float_as_uint(x.y - __uint_as_float(u1 & 0xFFFF0000u));
  unsigned r2 = __float_as_uint(x.z - __uint_as_float(u2 & 0xFFFF0000u));
  unsigned r3 = __float_as_uint(x.w - __uint_as_float(u3 & 0xFFFF0000u));
  lw[0] = __builtin_amdgcn_perm(r1, r0, 0x07060302u);
  lw[1] = __builtin_amdgcn_perm(r3, r2, 0x07060302u);
}
__device__ __forceinline__ void split1(float v, unsigned short& h, unsigned short& l) {
  unsigned u = __float_as_uint(v);
  h = (unsigned short)(u >> 16);
  float rr = v - __uint_as_float(u & 0xFFFF0000u);
  l = (unsigned short)(__float_as_uint(rr) >> 16);
}
__device__ __forceinline__ unsigned short bfr_rne(float v) {   // fp32->bf16 RNE
  unsigned u = __float_as_uint(v);
  return (unsigned short)((u + 0x7FFFu + ((u >> 16) & 1u)) >> 16);
}

// ---------------------------------------------------------------------------
// Kernel 0: convert W (3 x [128][1024] fp32) to hi/lo bf16 planes (flat).
// ---------------------------------------------------------------------------
__global__ __launch_bounds__(256) void wconv_kernel(
    const float* __restrict__ Wq, const float* __restrict__ Wk, const float* __restrict__ Wv,
    unsigned short* __restrict__ Whi, unsigned short* __restrict__ Wlo) {
  const float* W = blockIdx.y == 0 ? Wq : blockIdx.y == 1 ? Wk : Wv;
  size_t base = (size_t)blockIdx.y * DQK * DIN;
  int e = (blockIdx.x * 256 + threadIdx.x) * 4;
  float4 x = *(const float4*)&W[e];
  unsigned hw[2], lw[2];
  split4(x, hw, lw);
  *(uint2*)&Whi[base + e] = make_uint2(hw[0], hw[1]);
  *(uint2*)&Wlo[base + e] = make_uint2(lw[0], lw[1]);
}

// ---------------------------------------------------------------------------
// Kernel 1: projections via bf16 MFMA with hi/lo split (fp32-accurate).
// 64x128 block tile (grid 256x3 = 768 blocks = exactly 3/CU), 4 waves of
// 32x64 (2x4 of 16x16x32), K-chunk 64, 48KB LDS -> 3 blocks/CU resident.
// which 0/1 -> Q/K bf16 [s][d]; which 2 -> Vt single RNE bf16 [b][d][s].
// ---------------------------------------------------------------------------
__global__ __launch_bounds__(256, 3) void proj_kernel(
    const float* __restrict__ xq, const float* __restrict__ xk, const float* __restrict__ xv,
    const unsigned short* __restrict__ Whi, const unsigned short* __restrict__ Wlo,
    const float* __restrict__ bq, const float* __restrict__ bk, const float* __restrict__ bv,
    unsigned short* __restrict__ Qb, unsigned short* __restrict__ Kb,
    unsigned short* __restrict__ Vth) {
  const int which = blockIdx.y;
  const float* X    = which == 0 ? xq : which == 1 ? xk : xv;
  const float* bias = which == 0 ? bq : which == 1 ? bk : bv;
  const int m0 = blockIdx.x * 64;

  __shared__ unsigned short Xh[64 * 64];    // 8KB
  __shared__ unsigned short Xl[64 * 64];    // 8KB
  __shared__ unsigned short Wh[128 * 64];   // 16KB (reused as VH in V epilogue)
  __shared__ unsigned short Wl[128 * 64];   // 16KB

  const int tid = threadIdx.x;
  const int w = tid >> 6, lane = tid & 63, l15 = lane & 15, quad = lane >> 4;
  const int mh = (w >> 1) * 32, nh = (w & 1) * 64;

  floatx4 acc[2][4] = {};
  float biasv[4];
#pragma unroll
  for (int j = 0; j < 4; ++j) biasv[j] = bias[nh + j * 16 + l15];

  const unsigned short* WhiP = Whi + (size_t)which * DQK * DIN;
  const unsigned short* WloP = Wlo + (size_t)which * DQK * DIN;

  for (int kb = 0; kb < DIN; kb += 64) {
    __syncthreads();
    // --- stage X: fp32 -> hi/lo bf16 (trunc+perm), swizzled ---
#pragma unroll
    for (int i = 0; i < 4; ++i) {
      int f = tid + i * 256;
      int r = f >> 4, c4 = f & 15;
      float4 x = *(const float4*)&X[(size_t)(m0 + r) * DIN + kb + c4 * 4];
      unsigned hw[2], lw[2];
      split4(x, hw, lw);
      int off = r * 64 + (((c4 >> 1) ^ (r & 7)) * 8) + (c4 & 1) * 4;
      *(uint2*)&Xh[off] = make_uint2(hw[0], hw[1]);
      *(uint2*)&Xl[off] = make_uint2(lw[0], lw[1]);
    }
    // --- stage W hi/lo via global_load_lds (gather applies swizzle) ---
#pragma unroll
    for (int i = 0; i < 8; ++i) {
      int c = w * 8 + i;                 // 0..31: plane = c>>4, chunk cc = c&15
      int plane = c >> 4, cc = c & 15;
      int F = cc * 1024 + lane * 16;     // byte in 16KB plane tile
      int n = F >> 7, gs = (F >> 4) & 7, gl = gs ^ (n & 7);
      const unsigned short* gp = (plane ? WloP : WhiP) + (size_t)n * DIN + kb + gl * 8;
      ldsld16(gp, (char*)(plane ? Wl : Wh) + cc * 1024);
    }
    __syncthreads();
    // --- MFMA: 2 k-steps of 32, hi/lo 3-term product ---
#pragma unroll
    for (int ks = 0; ks < 2; ++ks) {
      short8 Ah[2], Al[2], Bh[4], Bl[4];
#pragma unroll
      for (int ms = 0; ms < 2; ++ms) {
        int off = (mh + ms * 16 + l15) * 64 + (((ks * 4 + quad) ^ (l15 & 7)) * 8);
        Ah[ms] = *(const short8*)&Xh[off];
        Al[ms] = *(const short8*)&Xl[off];
      }
#pragma unroll
      for (int ns = 0; ns < 4; ++ns) {
        int off = (nh + ns * 16 + l15) * 64 + (((ks * 4 + quad) ^ (l15 & 7)) * 8);
        Bh[ns] = *(const short8*)&Wh[off];
        Bl[ns] = *(const short8*)&Wl[off];
      }
#pragma unroll
      for (int i = 0; i < 2; ++i)
#pragma unroll
        for (int j = 0; j < 4; ++j) {
          floatx4 c = acc[i][j];
          c = __builtin_amdgcn_mfma_f32_16x16x32_bf16(Ah[i], Bh[j], c, 0, 0, 0);
          c = __builtin_amdgcn_mfma_f32_16x16x32_bf16(Ah[i], Bl[j], c, 0, 0, 0);
          c = __builtin_amdgcn_mfma_f32_16x16x32_bf16(Al[i], Bh[j], c, 0, 0, 0);
          acc[i][j] = c;
        }
    }
  }

  // --- epilogue ---
  if (which < 2) {
    unsigned short* O = which == 0 ? Qb : Kb;
#pragma unroll
    for (int i = 0; i < 2; ++i)
#pragma unroll
      for (int j = 0; j < 4; ++j)
#pragma unroll
        for (int r = 0; r < 4; ++r) {
          int m = mh + i * 16 + quad * 4 + r;
          int n = nh + j * 16 + l15;
          O[(size_t)(m0 + m) * DQK + n] = bfr_rne(acc[i][j][r] + biasv[j]);
        }
  } else {
    // V: add bias, single RNE bf16, transpose to [d][s] via LDS (reuse Wh)
    __syncthreads();
    unsigned short* VH = Wh;   // 128(d) x 64(s) bf16, swizzled
#pragma unroll
    for (int i = 0; i < 2; ++i)
#pragma unroll
      for (int j = 0; j < 4; ++j)
#pragma unroll
        for (int r = 0; r < 4; ++r) {
          int s = mh + i * 16 + quad * 4 + r;
          int d = nh + j * 16 + l15;
          VH[d * 64 + (((s >> 3) ^ (d & 7)) * 8) + (s & 7)] =
              bfr_rne(acc[i][j][r] + biasv[j]);
        }
    __syncthreads();
    int b = m0 >> 11, s0 = m0 & 2047;
#pragma unroll
    for (int i = 0; i < 4; ++i) {
      int cch = i * 256 + tid;          // 1024 16B-chunks
      int d = cch >> 3, gI = cch & 7;
      int loff = d * 64 + ((gI ^ (d & 7)) * 8);
      intx4 vh = *(const intx4*)&VH[loff];
      *(intx4*)&Vth[((size_t)b * DQK + d) * SEQ + s0 + gI * 8] = vh;
    }
  }
}

// ---------------------------------------------------------------------------
// Kernel 2: flash attention, MFMA, 3-way split-KV (kt % 3 classes).
// grid.x = 96 (qt = x/3, s = x%3), grid.y = batch -> 768 blocks = 3/CU
// (50KB LDS, __launch_bounds__(256,3)). V single bf16 plane; P kept hi/lo
// (2-term PV). Writes UNNORMALIZED partial O + (m,l); merge3 combines.
// ---------------------------------------------------------------------------
__global__ __launch_bounds__(256, 3) void attn_kernel(
    const unsigned short* __restrict__ Qb, const unsigned short* __restrict__ Kb,
    const unsigned short* __restrict__ Vth,
    float* __restrict__ Opart, float2* __restrict__ ML, GM g, unsigned int t64) {
  __shared__ unsigned short Ks[64 * 128];   // swizzled, 16KB
  __shared__ unsigned short Vh[128 * 64];   // swizzled, 16KB
  __shared__ unsigned short Ph[4][16 * 72]; // per-wave P hi strips (stride 72)
  __shared__ unsigned short Pl[4][16 * 72]; // per-wave P lo strips

  const int tid = threadIdx.x;
  const int w = tid >> 6, lane = tid & 63, l15 = lane & 15, quad = lane >> 4;
  const int b = blockIdx.y;
  const int qt = blockIdx.x / 3, s3 = blockIdx.x - qt * 3;
  const int qs = qt * 64;

  // Q fragments (A-layout), held in registers for the whole block
  short8 qf[4];
  const unsigned short* Qrow = Qb + ((size_t)(b * SEQ + qs + w * 16 + l15)) * DQK;
#pragma unroll
  for (int j = 0; j < 4; ++j) qf[j] = *(const short8*)&Qrow[j * 32 + quad * 8];

  int rowi[4]; bool growb[4];
#pragma unroll
  for (int r = 0; r < 4; ++r) {
    rowi[r] = qs + w * 16 + quad * 4 + r;
    growb[r] = gbit(g, rowi[r]);
  }

  floatx4 o[8] = {};
  float m_r[4] = {-1e30f, -1e30f, -1e30f, -1e30f};
  float l_r[4] = {0.f, 0.f, 0.f, 0.f};

  const bool qhasg = (t64 >> qt) & 1;
  const unsigned short* KbB = Kb  + (size_t)b * SEQ * DQK;
  const unsigned short* VhB = Vth + (size_t)b * DQK * SEQ;

  for (int kt = s3; kt < 32; kt += 3) {    // 3-way split-KV
    const int ks0 = kt * 64;
    if (!((ks0 <= qs + 63) || ((t64 >> kt) & 1) || qhasg)) continue;   // block-uniform

    __syncthreads();   // prior tile's LDS reads complete
    // --- stage K / Vt (32 x 1KB chunks, swizzled gather) ---
#pragma unroll
    for (int i = 0; i < 8; ++i) {
      int c = w * 8 + i;
      if (c < 16) {
        int F = c * 1024 + lane * 16;
        int r = F >> 8, gs = (F >> 4) & 15, gl = gs ^ (r & 15);
        ldsld16(KbB + (size_t)(ks0 + r) * DQK + gl * 8, (char*)Ks + c * 1024);
      } else {
        int cc = c - 16;
        int F = cc * 1024 + lane * 16;
        int d = F >> 7, gs = (F >> 4) & 7, gl = gs ^ (d & 7);
        ldsld16(VhB + (size_t)d * SEQ + ks0 + gl * 8, (char*)Vh + cc * 1024);
      }
    }
    __syncthreads();   // staging visible

    // --- QK^T: S strip [16 q x 64 k] per wave ---
    floatx4 S[4];
#pragma unroll
    for (int c4 = 0; c4 < 4; ++c4) {
      floatx4 s = {0.f, 0.f, 0.f, 0.f};
#pragma unroll
      for (int j = 0; j < 4; ++j) {
        short8 kf = *(const short8*)&Ks[(c4 * 16 + l15) * 128 + (((j * 4 + quad) ^ l15) * 8)];
        s = __builtin_amdgcn_mfma_f32_16x16x32_bf16(qf[j], kf, s, 0, 0, 0);
      }
      S[c4] = s;
    }

    // --- mask + scale + online softmax ---
    float z[4][4];
    float mx[4] = {-1e30f, -1e30f, -1e30f, -1e30f};
#pragma unroll
    for (int c4 = 0; c4 < 4; ++c4) {
      int col = ks0 + c4 * 16 + l15;
      bool cg = gbit(g, col);
#pragma unroll
      for (int r = 0; r < 4; ++r) {
        bool ok = (col <= rowi[r]) || cg || growb[r];
        float zz = ok ? S[c4][r] * INV_SCALE : -1e30f;
        z[c4][r] = zz;
        mx[r] = fmaxf(mx[r], zz);
      }
    }
#pragma unroll
    for (int d = 1; d < 16; d <<= 1)
#pragma unroll
      for (int r = 0; r < 4; ++r) mx[r] = fmaxf(mx[r], __shfl_xor(mx[r], d));
    float alpha[4], rs[4] = {0.f, 0.f, 0.f, 0.f};
#pragma unroll
    for (int r = 0; r < 4; ++r) {
      float mn = fmaxf(m_r[r], mx[r]);
      alpha[r] = __expf(m_r[r] - mn);
      m_r[r] = mn;
    }
    float p[4][4];
#pragma unroll
    for (int c4 = 0; c4 < 4; ++c4)
#pragma unroll
      for (int r = 0; r < 4; ++r) {
        float pp = __expf(z[c4][r] - m_r[r]);
        p[c4][r] = pp;
        rs[r] += pp;
      }
#pragma unroll
    for (int d = 1; d < 16; d <<= 1)
#pragma unroll
      for (int r = 0; r < 4; ++r) rs[r] += __shfl_xor(rs[r], d);
#pragma unroll
    for (int r = 0; r < 4; ++r) l_r[r] = l_r[r] * alpha[r] + rs[r];
#pragma unroll
    for (int n = 0; n < 8; ++n)
#pragma unroll
      for (int r = 0; r < 4; ++r) o[n][r] *= alpha[r];

    // --- P (C-layout) -> per-wave LDS strip as hi/lo bf16 (trunc split) ---
#pragma unroll
    for (int c4 = 0; c4 < 4; ++c4)
#pragma unroll
      for (int r = 0; r < 4; ++r) {
        unsigned short h, lo;
        split1(p[c4][r], h, lo);
        int off = (quad * 4 + r) * 72 + c4 * 16 + l15;
        Ph[w][off] = h; Pl[w][off] = lo;
      }
    short8 pf[2], pg[2];
#pragma unroll
    for (int kq = 0; kq < 2; ++kq) {
      int off = l15 * 72 + kq * 32 + quad * 8;
      pf[kq] = *(const short8*)&Ph[w][off];
      pg[kq] = *(const short8*)&Pl[w][off];
    }

    // --- PV: O[16 x 128] += P @ V (P hi/lo x V single = 2-term) ---
#pragma unroll
    for (int n = 0; n < 8; ++n) {
      int drow = n * 16 + l15;
#pragma unroll
      for (int kq = 0; kq < 2; ++kq) {
        int off = drow * 64 + (((kq * 4 + quad) ^ (drow & 7)) * 8);
        short8 vhf = *(const short8*)&Vh[off];
        floatx4 c = o[n];
        c = __builtin_amdgcn_mfma_f32_16x16x32_bf16(pf[kq], vhf, c, 0, 0, 0);
        c = __builtin_amdgcn_mfma_f32_16x16x32_bf16(pg[kq], vhf, c, 0, 0, 0);
        o[n] = c;
      }
    }
  }

  // --- epilogue: write UNNORMALIZED partial + (m,l) ---
  const size_t grp = (size_t)(b * 32 + qt) * 3 + s3;
  float* Op = Opart + grp * 64 * 128;
#pragma unroll
  for (int n = 0; n < 8; ++n)
#pragma unroll
    for (int r = 0; r < 4; ++r)
      Op[(w * 16 + quad * 4 + r) * 128 + n * 16 + l15] = o[n][r];
  if (l15 == 0) {
#pragma unroll
    for (int r = 0; r < 4; ++r)
      ML[grp * 64 + w * 16 + quad * 4 + r] = make_float2(m_r[r], l_r[r]);
  }
}

// ---------------------------------------------------------------------------
// Kernel 3: merge the three split-KV partials.
// out = sum_i w_i O_i / sum_i w_i l_i,  w_i = exp(m_i - max m).
// Empty part: m=-1e30, l=0, O=0 -> w_i==0 (diagonal tile guarantees one
// non-empty part per row group).
// ---------------------------------------------------------------------------
__global__ __launch_bounds__(256) void merge_kernel(
    const float* __restrict__ Opart, const float2* __restrict__ ML,
    float* __restrict__ Out) {
  const int t = threadIdx.x;
  const int row = blockIdx.x * 2 + (t >> 7);   // 0..16383
  const int col = t & 127;
  const int grp = row >> 6;                    // b*32 + qt
  const int rin = row & 63;
  const size_t base = (size_t)grp * 3;
  float2 ml0 = ML[(base + 0) * 64 + rin];
  float2 ml1 = ML[(base + 1) * 64 + rin];
  float2 ml2 = ML[(base + 2) * 64 + rin];
  const float m = fmaxf(fmaxf(ml0.x, ml1.x), ml2.x);
  const float w0 = __expf(ml0.x - m), w1 = __expf(ml1.x - m), w2 = __expf(ml2.x - m);
  const float denom = w0 * ml0.y + w1 * ml1.y + w2 * ml2.y;
  const float o0 = Opart[((base + 0) * 64 + rin) * 128 + col];
  const float o1 = Opart[((base + 1) * 64 + rin) * 128 + col];
  const float o2 = Opart[((base + 2) * 64 + rin) * 128 + col];
  Out[(size_t)row * 128 + col] = (w0 * o0 + w1 * o1 + w2 * o2) / denom;
}

// ---------------------------------------------------------------------------
extern "C" void kernel_launch(void* const* d_in, const int* in_sizes, int n_in,
                              void* d_out, int out_size, void* d_ws, size_t ws_size,
                              hipStream_t stream) {
  const float* q  = (const float*)d_in[0];
  const float* k  = (const float*)d_in[1];
  const float* v  = (const float*)d_in[2];
  const float* Wq = (const float*)d_in[3];
  const float* bq = (const float*)d_in[4];
  const float* Wk = (const float*)d_in[5];
  const float* bk = (const float*)d_in[6];
  const float* Wv = (const float*)d_in[7];
  const float* bv = (const float*)d_in[8];
  float* out = (float*)d_out;

  unsigned short* Qb  = (unsigned short*)d_ws;                 // 4MB bf16 [s][d]
  unsigned short* Kb2 = Qb  + (size_t)MTOT * DQK;              // 4MB
  unsigned short* Vth = Kb2 + (size_t)MTOT * DQK;              // 4MB  [b][d][s]
  unsigned short* Whi = Vth + (size_t)MTOT * DQK;              // 768KB
  unsigned short* Wlo = Whi + (size_t)3 * DQK * DIN;           // 768KB
  float*  Opart = (float*)(Wlo + (size_t)3 * DQK * DIN);       // 24MB partials
  float2* ML    = (float2*)(Opart + (size_t)3 * MTOT * DQK);   // 384KB (m,l)

  GM g;
  compute_gtok(g.w);
  unsigned int t64 = 0;
  for (int t = 0; t < 32; ++t) if (g.w[t] != 0ULL) t64 |= (1u << t);

  hipLaunchKernelGGL(wconv_kernel, dim3(128, 3), dim3(256), 0, stream,
                     Wq, Wk, Wv, Whi, Wlo);
  hipLaunchKernelGGL(proj_kernel, dim3(256, 3), dim3(256), 0, stream,
                     q, k, v, Whi, Wlo, bq, bk, bv, Qb, Kb2, Vth);
  hipLaunchKernelGGL(attn_kernel, dim3(96, 8), dim3(256), 0, stream,
                     Qb, Kb2, Vth, Opart, ML, g, t64);
  hipLaunchKernelGGL(merge_kernel, dim3(MTOT / 2), dim3(256), 0, stream,
                     Opart, ML, out);
}